// Round 3
// baseline (100.450 us; speedup 1.0000x reference)
//
#include <hip/hip_runtime.h>

// y = (2/pi) * atan(67 * x) / ln(67), elementwise, fp32.
// Memory-bound: 64M elements, 512 MiB HBM traffic -> ~85 us floor @ 6.3 TB/s.
// Fast branch-free atan approximation (poly err ~1e-5 rad; threshold 4.75e-3).
// Unroll x2: issue both nontemporal loads before compute/store for MLP.

typedef float f4 __attribute__((ext_vector_type(4)));

#define GAIN 67.0f
// (2.0/pi)/ln(67.0)
#define SCALE 0.15140697083726f
#define PIO2 1.5707963267948966f

__device__ __forceinline__ float atan_distort(float x) {
    float ax = __builtin_fabsf(x);
    float t = ax * GAIN;
    float r = __builtin_amdgcn_rcpf(t);   // v_rcp_f32, ~1 ulp
    bool big = t > 1.0f;
    float u = big ? r : t;                // u in [0,1]
    float u2 = u * u;
    float p = 0.0208351f;
    p = __builtin_fmaf(p, u2, -0.0851330f);
    p = __builtin_fmaf(p, u2, 0.1801410f);
    p = __builtin_fmaf(p, u2, -0.3302995f);
    p = __builtin_fmaf(p, u2, 0.9998660f);
    p = p * u;
    float a = big ? (PIO2 - p) : p;
    return __builtin_copysignf(a * SCALE, x);
}

__device__ __forceinline__ f4 atan_distort4(f4 v) {
    f4 o;
    o.x = atan_distort(v.x);
    o.y = atan_distort(v.y);
    o.z = atan_distort(v.z);
    o.w = atan_distort(v.w);
    return o;
}

__global__ __launch_bounds__(256) void ArcTanDistortion_54365696033609_kernel(
    const float* __restrict__ x, float* __restrict__ y, long long n) {
    long long n4 = n >> 2;
    const f4* __restrict__ x4 = (const f4*)x;
    f4* __restrict__ y4 = (f4*)y;

    long long tid = (long long)blockIdx.x * blockDim.x + threadIdx.x;
    long long stride = (long long)gridDim.x * blockDim.x;

    // Unrolled-by-2 main loop: two independent loads in flight per iteration.
    long long i = tid;
    for (; i + stride < n4; i += 2 * stride) {
        f4 va = __builtin_nontemporal_load(&x4[i]);
        f4 vb = __builtin_nontemporal_load(&x4[i + stride]);
        f4 oa = atan_distort4(va);
        f4 ob = atan_distort4(vb);
        __builtin_nontemporal_store(oa, &y4[i]);
        __builtin_nontemporal_store(ob, &y4[i + stride]);
    }
    for (; i < n4; i += stride) {
        f4 v = __builtin_nontemporal_load(&x4[i]);
        __builtin_nontemporal_store(atan_distort4(v), &y4[i]);
    }

    // Scalar tail (n % 4 != 0) — no-op for n = 64M but kept for generality.
    long long tail_start = n4 << 2;
    for (long long j = tail_start + tid; j < n; j += stride) {
        y[j] = atan_distort(x[j]);
    }
}

extern "C" void kernel_launch(void* const* d_in, const int* in_sizes, int n_in,
                              void* d_out, int out_size, void* d_ws, size_t ws_size,
                              hipStream_t stream) {
    const float* x = (const float*)d_in[0];
    float* y = (float*)d_out;
    long long n = (long long)in_sizes[0];

    const int block = 256;
    long long n4 = n >> 2;
    long long want = (n4 + block - 1) / block;
    int grid = (int)(want < 2048 ? (want > 0 ? want : 1) : 2048);

    ArcTanDistortion_54365696033609_kernel<<<grid, block, 0, stream>>>(x, y, n);
}

// Round 4
// 86.138 us; speedup vs baseline: 1.1662x; 1.1662x over previous
//
#include <hip/hip_runtime.h>

// y = (2/pi) * atan(67 * x) / ln(67), elementwise, fp32.
// Memory-bound: 64M elements, 512 MiB HBM traffic -> ~85 us floor @ 6.3 TB/s.
// Fast branch-free atan approximation (poly err ~1e-5 rad; threshold 4.75e-3).
// One-shot full grid: one float4 per thread, no loop -> load is the wave's
// first instruction, minimal VGPRs, max occupancy, dispatcher streams waves.

typedef float f4 __attribute__((ext_vector_type(4)));

#define GAIN 67.0f
// (2.0/pi)/ln(67.0)
#define SCALE 0.15140697083726f
#define PIO2 1.5707963267948966f

__device__ __forceinline__ float atan_distort(float x) {
    float ax = __builtin_fabsf(x);
    float t = ax * GAIN;
    float r = __builtin_amdgcn_rcpf(t);   // v_rcp_f32, ~1 ulp
    bool big = t > 1.0f;
    float u = big ? r : t;                // u in [0,1]
    float u2 = u * u;
    float p = 0.0208351f;
    p = __builtin_fmaf(p, u2, -0.0851330f);
    p = __builtin_fmaf(p, u2, 0.1801410f);
    p = __builtin_fmaf(p, u2, -0.3302995f);
    p = __builtin_fmaf(p, u2, 0.9998660f);
    p = p * u;
    float a = big ? (PIO2 - p) : p;
    return __builtin_copysignf(a * SCALE, x);
}

__global__ __launch_bounds__(256) void ArcTanDistortion_54365696033609_kernel(
    const float* __restrict__ x, float* __restrict__ y, long long n) {
    long long n4 = n >> 2;
    long long i = (long long)blockIdx.x * blockDim.x + threadIdx.x;

    if (i < n4) {
        const f4* __restrict__ x4 = (const f4*)x;
        f4* __restrict__ y4 = (f4*)y;
        f4 v = __builtin_nontemporal_load(&x4[i]);
        f4 o;
        o.x = atan_distort(v.x);
        o.y = atan_distort(v.y);
        o.z = atan_distort(v.z);
        o.w = atan_distort(v.w);
        __builtin_nontemporal_store(o, &y4[i]);
    }

    // Scalar tail (n % 4 != 0) — no-op for n = 64M but kept for generality.
    long long tail_start = n4 << 2;
    long long j = tail_start + i;
    if (j < n) {
        y[j] = atan_distort(x[j]);
    }
}

extern "C" void kernel_launch(void* const* d_in, const int* in_sizes, int n_in,
                              void* d_out, int out_size, void* d_ws, size_t ws_size,
                              hipStream_t stream) {
    const float* x = (const float*)d_in[0];
    float* y = (float*)d_out;
    long long n = (long long)in_sizes[0];

    const int block = 256;
    long long n4 = n >> 2;
    long long blocks = (n4 + block - 1) / block;
    if (blocks < 1) blocks = 1;

    ArcTanDistortion_54365696033609_kernel<<<(int)blocks, block, 0, stream>>>(x, y, n);
}